// Round 6
// baseline (501.826 us; speedup 1.0000x reference)
//
#include <hip/hip_runtime.h>
#include <math.h>

#define MDIM 512
#define NDIM 512
#define KDIM 512
#define MN (MDIM * NDIM)

#define BM 64
#define BN 64
#define BK 8
#define LSTR 68   // padded LDS row stride (floats); rows 16B-aligned

// SC encoding collapses to: ax = m*2^e (frexp), q = floor(m*L) (exact),
// v = sign * 2^(e+shAdj), shAdj = -log2(L) for A, 0 for B. dataWidth cancels.
// min(q1,q2) == thermometer AND-popcount (both sequences are thermometer codes).
__device__ __forceinline__ void sc_encode(float x, int shAdj, float Lf,
                                          float& v, float& q) {
    float ax = fabsf(x);
    v = 0.0f; q = 0.0f;
    if (ax > 0.0f) {
        int e;
        float m = frexpf(ax, &e);          // ax = m * 2^e, m in [0.5,1)
        q = floorf(m * Lf);                // exact f32 product
        v = ldexpf((x > 0.0f) ? 1.0f : -1.0f, e + shAdj);
    }
}

// Fused SC-encode + min-GEMM (approx) + f32 GEMM (exact).
// 64-thread single-wave blocks, 8x8 micro-tile (balanced: LDS ~7.7us vs VALU
// ~6.8us per-CU at m134's 85 B/cyc b128 throughput). KS=32 -> 2048 waves =
// 2 waves/SIMD (R5 at KS=16 had 1/SIMD and was latency-exposed: 33us).
// BK=8 keeps LDS at 13KB so VGPR (not LDS) sets the 8-blocks/CU residency.
template<int KS>
__global__ __launch_bounds__(64, 2) void sc_gemm_k(
        const float* __restrict__ t1, const float* __restrict__ t2,
        float* __restrict__ dst, float Lf, int logL) {
    __shared__ __align__(16) float As_v[BK][LSTR];
    __shared__ __align__(16) float As_q[BK][LSTR];
    __shared__ __align__(16) float As_t[BK][LSTR];
    __shared__ __align__(16) float Bs_v[BK][LSTR];
    __shared__ __align__(16) float Bs_q[BK][LSTR];
    __shared__ __align__(16) float Bs_t[BK][LSTR];

    const int tid = threadIdx.x;
    const int tx = tid & 7;           // n-dir, 8 cols of 8
    const int ty = tid >> 3;          // m-dir, 8 rows of 8
    const int n0 = blockIdx.x * BN;
    const int m0 = blockIdx.y * BM;
    const int kbase = blockIdx.z * (KDIM / KS);

    float acc[8][8] = {};
    float acce[8][8] = {};

    #pragma unroll
    for (int kt = 0; kt < (KDIM / KS) / BK; ++kt) {
        const int kk0 = kbase + kt * BK;
        if (kt) __syncthreads();

        // stage A tile (64 m-rows x 8 k): encode inline, transpose to [k][m]
        #pragma unroll
        for (int ff = 0; ff < 2; ++ff) {
            int f = tid + ff * 64;             // 128 float4s
            int row = f >> 1;                  // 0..63
            int c4  = (f & 1) << 2;            // k offset 0 or 4
            float4 t = *(const float4*)(t1 + (m0 + row) * KDIM + kk0 + c4);
            const float* tp = &t.x;
            #pragma unroll
            for (int d = 0; d < 4; ++d) {
                float v, q;
                sc_encode(tp[d], -logL, Lf, v, q);
                As_v[c4 + d][row] = v;
                As_q[c4 + d][row] = q;
                As_t[c4 + d][row] = tp[d];
            }
        }
        // stage B tile (8 k x 64 n): encode inline, natural [k][n]
        #pragma unroll
        for (int ff = 0; ff < 2; ++ff) {
            int f = tid + ff * 64;
            int rowk = f >> 4;                 // 0..7
            int c4   = (f & 15) << 2;          // 0..60
            float4 t = *(const float4*)(t2 + (kk0 + rowk) * NDIM + n0 + c4);
            float4 v4, q4;
            float* vp = &v4.x; float* qp = &q4.x; const float* tp = &t.x;
            #pragma unroll
            for (int d = 0; d < 4; ++d) sc_encode(tp[d], 0, Lf, vp[d], qp[d]);
            *(float4*)&Bs_v[rowk][c4] = v4;
            *(float4*)&Bs_q[rowk][c4] = q4;
            *(float4*)&Bs_t[rowk][c4] = t;
        }
        __syncthreads();

        #pragma unroll
        for (int kk = 0; kk < BK; ++kk) {
            float av[8], aq[8], at8[8], bv[8], bq[8], bt8[8];
            const int a0 = ty << 3, b0 = tx << 3;
            *(float4*)&av[0]  = *(const float4*)&As_v[kk][a0];
            *(float4*)&av[4]  = *(const float4*)&As_v[kk][a0 + 4];
            *(float4*)&aq[0]  = *(const float4*)&As_q[kk][a0];
            *(float4*)&aq[4]  = *(const float4*)&As_q[kk][a0 + 4];
            *(float4*)&at8[0] = *(const float4*)&As_t[kk][a0];
            *(float4*)&at8[4] = *(const float4*)&As_t[kk][a0 + 4];
            *(float4*)&bv[0]  = *(const float4*)&Bs_v[kk][b0];
            *(float4*)&bv[4]  = *(const float4*)&Bs_v[kk][b0 + 4];
            *(float4*)&bq[0]  = *(const float4*)&Bs_q[kk][b0];
            *(float4*)&bq[4]  = *(const float4*)&Bs_q[kk][b0 + 4];
            *(float4*)&bt8[0] = *(const float4*)&Bs_t[kk][b0];
            *(float4*)&bt8[4] = *(const float4*)&Bs_t[kk][b0 + 4];
            #pragma unroll
            for (int i = 0; i < 8; ++i) {
                #pragma unroll
                for (int j = 0; j < 8; ++j) {
                    acc[i][j]  = fmaf(av[i] * bv[j], fminf(aq[i], bq[j]), acc[i][j]);
                    acce[i][j] = fmaf(at8[i], bt8[j], acce[i][j]);
                }
            }
        }
    }

    // epilogue: streaming float4 partial stores (no atomics)
    float* o = dst + (size_t)blockIdx.z * (2 * MN);
    #pragma unroll
    for (int i = 0; i < 8; ++i) {
        int m = m0 + (ty << 3) + i;
        int nb = n0 + (tx << 3);
        *(float4*)&o[m * NDIM + nb]          = *(float4*)&acc[i][0];
        *(float4*)&o[m * NDIM + nb + 4]      = *(float4*)&acc[i][4];
        *(float4*)&o[MN + m * NDIM + nb]     = *(float4*)&acce[i][0];
        *(float4*)&o[MN + m * NDIM + nb + 4] = *(float4*)&acce[i][4];
    }
}

// Sum KS partial output images (each 2*MN floats) into d_out.
template<int KS>
__global__ __launch_bounds__(256) void reduce_k(const float4* __restrict__ ws,
                                                float4* __restrict__ out) {
    int i = blockIdx.x * blockDim.x + threadIdx.x;   // 0 .. 2*MN/4-1
    float4 s = ws[i];
    #pragma unroll
    for (int z = 1; z < KS; ++z) {
        float4 v = ws[(size_t)z * (2 * MN / 4) + i];
        s.x += v.x; s.y += v.y; s.z += v.z; s.w += v.w;
    }
    out[i] = s;
}

extern "C" void kernel_launch(void* const* d_in, const int* in_sizes, int n_in,
                              void* d_out, int out_size, void* d_ws, size_t ws_size,
                              hipStream_t stream) {
    const float* t1 = (const float*)d_in[0];
    const float* t2 = (const float*)d_in[1];
    // d_in[2] = rngSeq (arange -> thermometer code), d_in[3] = dataWidth (cancels)
    int L = in_sizes[2];
    int logL = 31 - __builtin_clz((unsigned)L);
    float Lf = (float)L;

    float* out = (float*)d_out;
    float* ws  = (float*)d_ws;
    const size_t perSplit = (size_t)2 * MN * sizeof(float);   // 2 MB
    const int nred = (2 * MN / 4) / 256;                      // 512 blocks

    if (ws_size >= 32 * perSplit) {
        hipLaunchKernelGGL((sc_gemm_k<32>), dim3(NDIM / BN, MDIM / BM, 32), dim3(64),
                           0, stream, t1, t2, ws, Lf, logL);
        hipLaunchKernelGGL((reduce_k<32>), dim3(nred), dim3(256), 0, stream,
                           (const float4*)ws, (float4*)out);
    } else if (ws_size >= 16 * perSplit) {
        hipLaunchKernelGGL((sc_gemm_k<16>), dim3(NDIM / BN, MDIM / BM, 16), dim3(64),
                           0, stream, t1, t2, ws, Lf, logL);
        hipLaunchKernelGGL((reduce_k<16>), dim3(nred), dim3(256), 0, stream,
                           (const float4*)ws, (float4*)out);
    } else {
        // no workspace: single-slice grid writes d_out directly (still no atomics)
        hipLaunchKernelGGL((sc_gemm_k<1>), dim3(NDIM / BN, MDIM / BM, 1), dim3(64),
                           0, stream, t1, t2, out, Lf, logL);
    }
}

// Round 9
// 88.192 us; speedup vs baseline: 5.6902x; 5.6902x over previous
//
#include <hip/hip_runtime.h>
#include <math.h>

#define MDIM 512
#define NDIM 512
#define KDIM 512
#define MN (MDIM * NDIM)

#define BM 64
#define BN 64
#define BK 32
#define LSTR 68   // padded LDS row stride (floats); rows 16B-aligned, 2-way banks (free)

// SC encoding, minimal-storage form. For x = s*m*2^e (frexp, m in [0.5,1)):
//   v = s * 2^(e+shAdj)   (pure power of two; shAdj=-log2L for A, 0 for B)
//   p = m * L             (exact f32 product)
// Recovery at compute time (all exact, power-of-2 scales):
//   q = floor(p)                       (bitstream popcount)
//   A: at = va*pa = s1*m1*2^e1 = x1    (va carries 2^-logL, pa carries L)
//   B: bt = vb*(pb*invL) = x2          (invL = 2^-logL exact)
__device__ __forceinline__ void sc_encode_vp(float x, int shAdj, float Lf,
                                             float& v, float& p) {
    float ax = fabsf(x);
    v = 0.0f; p = 0.0f;
    if (ax > 0.0f) {
        int e;
        float m = frexpf(ax, &e);          // ax = m * 2^e
        p = m * Lf;                        // exact; q = floor(p), in [L/2, L)
        v = ldexpf((x > 0.0f) ? 1.0f : -1.0f, e + shAdj);
    }
}

// Fused SC-encode + min-GEMM (approx) + f32 GEMM (exact).
// 256-thread blocks (R4's proven structure: VGPR 68, no spill), 4x4 micro-tile.
// (v,p) staging: 4 LDS arrays instead of 6 -> 4 B/MAC (LDS floor ~10.3us) at the
// cost of 16 prep VALU/kk-thread (VALU floor ~8.5us). LDS 35KB -> 4 blocks/CU;
// KS=16 -> 1024 blocks = 4/CU = 4 waves/SIMD, K-chunk==BK (single stage phase).
template<int KS>
__global__ __launch_bounds__(256) void sc_gemm_k(
        const float* __restrict__ t1, const float* __restrict__ t2,
        float* __restrict__ dst, float Lf, float invL, int logL) {
    __shared__ __align__(16) float As_v[BK][LSTR];
    __shared__ __align__(16) float As_p[BK][LSTR];
    __shared__ __align__(16) float Bs_v[BK][LSTR];
    __shared__ __align__(16) float Bs_p[BK][LSTR];

    const int tid = threadIdx.x;
    const int tx = tid & 15;
    const int ty = tid >> 4;
    const int n0 = blockIdx.x * BN;
    const int m0 = blockIdx.y * BM;
    const int kbase = blockIdx.z * (KDIM / KS);

    float acc[4][4] = {};
    float acce[4][4] = {};

    for (int kt = 0; kt < (KDIM / KS) / BK; ++kt) {   // 1 iteration at KS=16
        const int kk0 = kbase + kt * BK;
        if (kt) __syncthreads();

        // stage A tile (64 m-rows x 32 k): encode inline, transpose to [k][m]
        #pragma unroll
        for (int ff = 0; ff < 2; ++ff) {
            int f = tid + ff * 256;            // 512 float4s
            int row = f >> 3;                  // 0..63
            int c4  = (f & 7) << 2;            // k offset 0..28
            float4 t = *(const float4*)(t1 + (m0 + row) * KDIM + kk0 + c4);
            const float* tp = &t.x;
            #pragma unroll
            for (int d = 0; d < 4; ++d) {
                float v, p;
                sc_encode_vp(tp[d], -logL, Lf, v, p);
                As_v[c4 + d][row] = v;
                As_p[c4 + d][row] = p;
            }
        }
        // stage B tile (32 k x 64 n): encode inline, natural [k][n]
        #pragma unroll
        for (int ff = 0; ff < 2; ++ff) {
            int f = tid + ff * 256;
            int rowk = f >> 4;                 // 0..31
            int c4   = (f & 15) << 2;          // 0..60
            float4 t = *(const float4*)(t2 + (kk0 + rowk) * NDIM + n0 + c4);
            float4 v4, p4;
            float* vp = &v4.x; float* pp = &p4.x; const float* tp = &t.x;
            #pragma unroll
            for (int d = 0; d < 4; ++d) sc_encode_vp(tp[d], 0, Lf, vp[d], pp[d]);
            *(float4*)&Bs_v[rowk][c4] = v4;
            *(float4*)&Bs_p[rowk][c4] = p4;
        }
        __syncthreads();

        #pragma unroll 8
        for (int kk = 0; kk < BK; ++kk) {
            float av[4], ap[4], bv[4], bp[4];
            *(float4*)av = *(const float4*)&As_v[kk][ty << 2];
            *(float4*)ap = *(const float4*)&As_p[kk][ty << 2];
            *(float4*)bv = *(const float4*)&Bs_v[kk][tx << 2];
            *(float4*)bp = *(const float4*)&Bs_p[kk][tx << 2];
            float aq[4], at[4], bq[4], bt[4];
            #pragma unroll
            for (int i = 0; i < 4; ++i) {
                aq[i] = floorf(ap[i]);
                at[i] = av[i] * ap[i];          // == original t1 value (exact)
                bq[i] = floorf(bp[i]);
                bt[i] = bv[i] * (bp[i] * invL); // == original t2 value (exact)
            }
            #pragma unroll
            for (int i = 0; i < 4; ++i) {
                #pragma unroll
                for (int j = 0; j < 4; ++j) {
                    acc[i][j]  = fmaf(av[i] * bv[j], fminf(aq[i], bq[j]), acc[i][j]);
                    acce[i][j] = fmaf(at[i], bt[j], acce[i][j]);
                }
            }
        }
    }

    // epilogue: streaming float4 partial stores (no atomics)
    float* o = dst + (size_t)blockIdx.z * (2 * MN);
    #pragma unroll
    for (int i = 0; i < 4; ++i) {
        int m = m0 + (ty << 2) + i;
        int nb = n0 + (tx << 2);
        float4 va = { acc[i][0],  acc[i][1],  acc[i][2],  acc[i][3] };
        float4 ve = { acce[i][0], acce[i][1], acce[i][2], acce[i][3] };
        *(float4*)&o[m * NDIM + nb]      = va;
        *(float4*)&o[MN + m * NDIM + nb] = ve;
    }
}

// Sum KS partial output images (each 2*MN floats) into d_out.
template<int KS>
__global__ __launch_bounds__(256) void reduce_k(const float4* __restrict__ ws,
                                                float4* __restrict__ out) {
    int i = blockIdx.x * blockDim.x + threadIdx.x;   // 0 .. 2*MN/4-1
    float4 s = ws[i];
    #pragma unroll
    for (int z = 1; z < KS; ++z) {
        float4 v = ws[(size_t)z * (2 * MN / 4) + i];
        s.x += v.x; s.y += v.y; s.z += v.z; s.w += v.w;
    }
    out[i] = s;
}

extern "C" void kernel_launch(void* const* d_in, const int* in_sizes, int n_in,
                              void* d_out, int out_size, void* d_ws, size_t ws_size,
                              hipStream_t stream) {
    const float* t1 = (const float*)d_in[0];
    const float* t2 = (const float*)d_in[1];
    // d_in[2] = rngSeq (arange -> thermometer code), d_in[3] = dataWidth (cancels)
    int L = in_sizes[2];
    int logL = 31 - __builtin_clz((unsigned)L);
    float Lf = (float)L;
    float invL = 1.0f / Lf;                  // exact power of two

    float* out = (float*)d_out;
    float* ws  = (float*)d_ws;
    const size_t perSplit = (size_t)2 * MN * sizeof(float);   // 2 MB
    const int nred = (2 * MN / 4) / 256;                      // 512 blocks

    if (ws_size >= 16 * perSplit) {
        hipLaunchKernelGGL((sc_gemm_k<16>), dim3(NDIM / BN, MDIM / BM, 16), dim3(256),
                           0, stream, t1, t2, ws, Lf, invL, logL);
        hipLaunchKernelGGL((reduce_k<16>), dim3(nred), dim3(256), 0, stream,
                           (const float4*)ws, (float4*)out);
    } else if (ws_size >= 8 * perSplit) {
        hipLaunchKernelGGL((sc_gemm_k<8>), dim3(NDIM / BN, MDIM / BM, 8), dim3(256),
                           0, stream, t1, t2, ws, Lf, invL, logL);
        hipLaunchKernelGGL((reduce_k<8>), dim3(nred), dim3(256), 0, stream,
                           (const float4*)ws, (float4*)out);
    } else {
        // no workspace: single-slice grid writes d_out directly (still no atomics)
        hipLaunchKernelGGL((sc_gemm_k<1>), dim3(NDIM / BN, MDIM / BM, 1), dim3(256),
                           0, stream, t1, t2, out, Lf, invL, logL);
    }
}